// Round 12
// baseline (1663.090 us; speedup 1.0000x reference)
//
#include <hip/hip_runtime.h>

// ---------------------------------------------------------------------------
// Problem constants (B=16, N=128, FIN=D=512)
// ---------------------------------------------------------------------------
#define BATCH 16
#define NNODE 128
#define DIM 512
#define NP1 129              // N+1 (with virtual node)
#define EDSZ (NP1 * NP1)     // 16641 per batch
#define BIGF 3.0e38f         // sentinel (finite)

// ---------------------------------------------------------------------------
// Fused dual-input GEMM (NT): Y{0,1}[m][n] = relu(sum_k X{0,1}[m][k]*W[n][k]+b[n])
// ---------------------------------------------------------------------------
__global__ __launch_bounds__(256) void gemm2_nt_relu(
    const float* __restrict__ X0, const float* __restrict__ X1,
    const float* __restrict__ W, const float* __restrict__ bias,
    float* __restrict__ Y0, float* __restrict__ Y1,
    int M, int N, int K) {
  const float* X = blockIdx.z ? X1 : X0;
  float* Y = blockIdx.z ? Y1 : Y0;
  __shared__ float sA[32][68];
  __shared__ float sB[32][68];
  const int tid = threadIdx.x;
  const int m0 = blockIdx.x * 64;
  const int n0 = blockIdx.y * 64;
  const int tm = tid / 16, tn = tid % 16;
  const int lr = tid >> 2;
  const int lk8 = (tid & 3) * 8;
  float acc[4][4] = {};
  for (int k0 = 0; k0 < K; k0 += 32) {
    const float* xa = X + (size_t)(m0 + lr) * K + k0 + lk8;
    const float* wb = W + (size_t)(n0 + lr) * K + k0 + lk8;
    float4 a0 = *(const float4*)(xa);
    float4 a1 = *(const float4*)(xa + 4);
    float4 b0 = *(const float4*)(wb);
    float4 b1 = *(const float4*)(wb + 4);
    sA[lk8 + 0][lr] = a0.x; sA[lk8 + 1][lr] = a0.y;
    sA[lk8 + 2][lr] = a0.z; sA[lk8 + 3][lr] = a0.w;
    sA[lk8 + 4][lr] = a1.x; sA[lk8 + 5][lr] = a1.y;
    sA[lk8 + 6][lr] = a1.z; sA[lk8 + 7][lr] = a1.w;
    sB[lk8 + 0][lr] = b0.x; sB[lk8 + 1][lr] = b0.y;
    sB[lk8 + 2][lr] = b0.z; sB[lk8 + 3][lr] = b0.w;
    sB[lk8 + 4][lr] = b1.x; sB[lk8 + 5][lr] = b1.y;
    sB[lk8 + 6][lr] = b1.z; sB[lk8 + 7][lr] = b1.w;
    __syncthreads();
#pragma unroll
    for (int k = 0; k < 32; ++k) {
      const float4 a = *(const float4*)&sA[k][tm * 4];
      const float4 b = *(const float4*)&sB[k][tn * 4];
      acc[0][0] = fmaf(a.x, b.x, acc[0][0]);
      acc[0][1] = fmaf(a.x, b.y, acc[0][1]);
      acc[0][2] = fmaf(a.x, b.z, acc[0][2]);
      acc[0][3] = fmaf(a.x, b.w, acc[0][3]);
      acc[1][0] = fmaf(a.y, b.x, acc[1][0]);
      acc[1][1] = fmaf(a.y, b.y, acc[1][1]);
      acc[1][2] = fmaf(a.y, b.z, acc[1][2]);
      acc[1][3] = fmaf(a.y, b.w, acc[1][3]);
      acc[2][0] = fmaf(a.z, b.x, acc[2][0]);
      acc[2][1] = fmaf(a.z, b.y, acc[2][1]);
      acc[2][2] = fmaf(a.z, b.z, acc[2][2]);
      acc[2][3] = fmaf(a.z, b.w, acc[2][3]);
      acc[3][0] = fmaf(a.w, b.x, acc[3][0]);
      acc[3][1] = fmaf(a.w, b.y, acc[3][1]);
      acc[3][2] = fmaf(a.w, b.z, acc[3][2]);
      acc[3][3] = fmaf(a.w, b.w, acc[3][3]);
    }
    __syncthreads();
  }
#pragma unroll
  for (int i = 0; i < 4; ++i) {
    int m = m0 + tm * 4 + i;
#pragma unroll
    for (int j = 0; j < 4; ++j) {
      int n = n0 + tn * 4 + j;
      Y[(size_t)m * N + n] = fmaxf(acc[i][j] + bias[n], 0.f);
    }
  }
}

// ---------------------------------------------------------------------------
// Virtual-node embed, both layers in ONE block (LDS hand-off).
// ---------------------------------------------------------------------------
__global__ __launch_bounds__(256) void virt_embed(
    const float* __restrict__ x,
    const float* __restrict__ W1, const float* __restrict__ b1,
    const float* __restrict__ W2, const float* __restrict__ b2,
    float* __restrict__ e_v) {
  __shared__ float sx[DIM];
  __shared__ float sh[DIM];
  for (int k = threadIdx.x; k < DIM; k += 256) sx[k] = x[k];
  __syncthreads();
  for (int n = threadIdx.x; n < DIM; n += 256) {
    const float* w = W1 + (size_t)n * DIM;
    float s = 0.f;
    for (int k = 0; k < DIM; k += 4) {
      float4 wv = *(const float4*)(w + k);
      s = fmaf(sx[k + 0], wv.x, s);
      s = fmaf(sx[k + 1], wv.y, s);
      s = fmaf(sx[k + 2], wv.z, s);
      s = fmaf(sx[k + 3], wv.w, s);
    }
    sh[n] = fmaxf(s + b1[n], 0.f);
  }
  __syncthreads();
  for (int n = threadIdx.x; n < DIM; n += 256) {
    const float* w = W2 + (size_t)n * DIM;
    float s = 0.f;
    for (int k = 0; k < DIM; k += 4) {
      float4 wv = *(const float4*)(w + k);
      s = fmaf(sh[k + 0], wv.x, s);
      s = fmaf(sh[k + 1], wv.y, s);
      s = fmaf(sh[k + 2], wv.z, s);
      s = fmaf(sh[k + 3], wv.w, s);
    }
    e_v[n] = fmaxf(s + b2[n], 0.f);
  }
}

// ---------------------------------------------------------------------------
// cdist: d[b][i][j] = || esrow(b,i) - etrow(b,j) ||_2
// ---------------------------------------------------------------------------
__global__ __launch_bounds__(256) void cdist_kernel(
    const float* __restrict__ es, const float* __restrict__ et,
    const float* __restrict__ ev, float* __restrict__ d) {
  const int b = blockIdx.z;
  const int i0 = blockIdx.x * 32;
  const int j0 = blockIdx.y * 32;
  __shared__ float sA[32][33];
  __shared__ float sB[32][33];
  const int tid = threadIdx.x;
  const int ty = tid / 16, tx = tid % 16;
  const int lr = tid / 8;
  const int lk4 = (tid % 8) * 4;
  const int gi = i0 + lr;
  const int gj = j0 + lr;
  const float* pa = (gi < NNODE) ? (es + ((size_t)b * NNODE + gi) * DIM) : ev;
  const float* pb = (gj < NNODE) ? (et + ((size_t)b * NNODE + gj) * DIM) : ev;
  float acc[2][2] = {};
  for (int k0 = 0; k0 < DIM; k0 += 32) {
    float4 av = *(const float4*)(pa + k0 + lk4);
    float4 bv = *(const float4*)(pb + k0 + lk4);
    sA[lr][lk4 + 0] = av.x; sA[lr][lk4 + 1] = av.y;
    sA[lr][lk4 + 2] = av.z; sA[lr][lk4 + 3] = av.w;
    sB[lr][lk4 + 0] = bv.x; sB[lr][lk4 + 1] = bv.y;
    sB[lr][lk4 + 2] = bv.z; sB[lr][lk4 + 3] = bv.w;
    __syncthreads();
#pragma unroll 8
    for (int k = 0; k < 32; ++k) {
      float a0 = sA[ty * 2 + 0][k], a1 = sA[ty * 2 + 1][k];
      float b0 = sB[tx * 2 + 0][k], b1 = sB[tx * 2 + 1][k];
      float d00 = a0 - b0, d01 = a0 - b1, d10 = a1 - b0, d11 = a1 - b1;
      acc[0][0] = fmaf(d00, d00, acc[0][0]);
      acc[0][1] = fmaf(d01, d01, acc[0][1]);
      acc[1][0] = fmaf(d10, d10, acc[1][0]);
      acc[1][1] = fmaf(d11, d11, acc[1][1]);
    }
    __syncthreads();
  }
#pragma unroll
  for (int i = 0; i < 2; ++i) {
    int gi2 = i0 + ty * 2 + i;
#pragma unroll
    for (int j = 0; j < 2; ++j) {
      int gj2 = j0 + tx * 2 + j;
      if (gi2 < NP1 && gj2 < NP1)
        d[(size_t)b * EDSZ + gi2 * NP1 + gj2] = sqrtf(acc[i][j]);
    }
  }
}

// ---------------------------------------------------------------------------
// Deterministic per-batch sum (fp64 tree)
// ---------------------------------------------------------------------------
__global__ __launch_bounds__(256) void batch_sum(
    const float* __restrict__ d, float* __restrict__ sums) {
  const int b = blockIdx.x;
  double s = 0.0;
  for (int idx = threadIdx.x; idx < EDSZ; idx += 256)
    s += (double)d[(size_t)b * EDSZ + idx];
  __shared__ double red[256];
  red[threadIdx.x] = s;
  __syncthreads();
  for (int off = 128; off; off >>= 1) {
    if (threadIdx.x < off) red[threadIdx.x] += red[threadIdx.x + off];
    __syncthreads();
  }
  if (threadIdx.x == 0) sums[b] = (float)red[0];
}

// ---------------------------------------------------------------------------
// normalize: edit = d / sum[b] * N*N
// ---------------------------------------------------------------------------
__global__ __launch_bounds__(256) void normalize_kernel(
    const float* __restrict__ d, const float* __restrict__ sums,
    float* __restrict__ edit) {
  int idx = blockIdx.x * 256 + threadIdx.x;
  if (idx < BATCH * EDSZ) {
    int b = idx / EDSZ;
    edit[idx] = d[idx] / sums[b] * (float)(NNODE * NNODE);
  }
}

// ---------------------------------------------------------------------------
// build_D: dense collapsed 128x128 LSAP cost per batch, from edit.
// Exactly the same float expression previously used in lsap staging.
// ---------------------------------------------------------------------------
__global__ __launch_bounds__(256) void build_D(
    const float* __restrict__ edit, float* __restrict__ Dg) {
  int idx = blockIdx.x * 256 + threadIdx.x;
  if (idx < BATCH * NNODE * NNODE) {
    const int b = idx >> 14;
    const int rc = idx & 16383;
    const int i = rc >> 7, j = rc & 127;
    const float* ec = edit + (size_t)b * EDSZ;
    Dg[idx] = fminf(ec[i * NP1 + j], ec[i * NP1 + NNODE] + ec[NNODE * NP1 + j]);
  }
}

// ---------------------------------------------------------------------------
// cross-lane helpers: 32-bit packed argmin on the VALU pipe.
// ---------------------------------------------------------------------------
__device__ __forceinline__ unsigned key_of(float m, int col) {
  return (__float_as_uint(m) & 0xFFFFFF80u) | (unsigned)col;
}

template <int CTRL>
__device__ __forceinline__ unsigned dpp_umin_step(unsigned x) {
  const unsigned o = (unsigned)__builtin_amdgcn_update_dpp(
      (int)0xFFFFFFFFu, (int)x, CTRL, 0xf, 0xf, false);
  return o < x ? o : x;
}

__device__ __forceinline__ unsigned wave_umin_key(unsigned x) {
  x = dpp_umin_step<0x111>(x);
  x = dpp_umin_step<0x112>(x);
  x = dpp_umin_step<0x114>(x);
  x = dpp_umin_step<0x118>(x);
  x = dpp_umin_step<0x142>(x);
  x = dpp_umin_step<0x143>(x);
  return (unsigned)__builtin_amdgcn_readlane((int)x, 63);
}

template <int CTRL>
__device__ __forceinline__ void dpp_umin2_step(unsigned& m1, unsigned& m2) {
  const unsigned o1 = (unsigned)__builtin_amdgcn_update_dpp(
      (int)0xFFFFFFFFu, (int)m1, CTRL, 0xf, 0xf, false);
  const unsigned o2 = (unsigned)__builtin_amdgcn_update_dpp(
      (int)0xFFFFFFFFu, (int)m2, CTRL, 0xf, 0xf, false);
  const unsigned lo = m1 < o1 ? m1 : o1;
  const unsigned hi = m1 < o1 ? o1 : m1;
  const unsigned yo = m2 < o2 ? m2 : o2;
  m1 = lo;
  m2 = hi < yo ? hi : yo;
}

__device__ __forceinline__ void wave_umin2_key(unsigned a, unsigned b,
                                               unsigned& k1, unsigned& k2) {
  unsigned m1 = a < b ? a : b;
  unsigned m2 = a < b ? b : a;
  dpp_umin2_step<0x111>(m1, m2);
  dpp_umin2_step<0x112>(m1, m2);
  dpp_umin2_step<0x114>(m1, m2);
  dpp_umin2_step<0x118>(m1, m2);
  dpp_umin2_step<0x142>(m1, m2);
  dpp_umin2_step<0x143>(m1, m2);
  k1 = (unsigned)__builtin_amdgcn_readlane((int)m1, 63);
  k2 = (unsigned)__builtin_amdgcn_readlane((int)m2, 63);
}

__device__ __forceinline__ float fsel2(float a0, float a1, int s) {
  return (s == 0) ? a0 : a1;
}
__device__ __forceinline__ int isel2(int a0, int a1, int s) {
  return (s == 0) ? a0 : a1;
}
__device__ __forceinline__ float readlane_f32(float x, int lane) {
  return __uint_as_float(
      (unsigned)__builtin_amdgcn_readlane((int)__float_as_uint(x), lane));
}

// ---------------------------------------------------------------------------
// lsap2: TWO interleaved LAPJV chains per wave (batches 2*bid, 2*bid+1).
// All state duplicated per chain; hot loops are unrolled c-loops of
// straight-line predicated code so the scheduler overlaps the two
// independent dependency chains (chain 0 rows from LDS, chain 1 rows from
// global Dg/L2 — loads issued together, latencies overlap). Each chain's
// fp32 op sequence is identical to the validated R10 kernel.
// ---------------------------------------------------------------------------
__global__ __launch_bounds__(64) void lsap2_kernel(
    const float* __restrict__ edit, const float* __restrict__ Dg,
    float* __restrict__ Aout, float* __restrict__ geds) {
  const int bid = blockIdx.x;          // 0..7
  const int lane = threadIdx.x;
  const int cbase = lane * 2;
  const float* DgA = Dg + (size_t)(2 * bid + 0) * (NNODE * NNODE);
  const float* DgB = Dg + (size_t)(2 * bid + 1) * (NNODE * NNODE);

  __shared__ float DL[NNODE * NNODE];  // chain 0's cost matrix (64 KB)

  for (int idx = lane * 4; idx < NNODE * NNODE; idx += 256)
    *(float4*)&DL[idx] = *(const float4*)&DgA[idx];
  {
    float* A0 = Aout + (size_t)(2 * bid + 0) * EDSZ;
    float* A1 = Aout + (size_t)(2 * bid + 1) * EDSZ;
    for (int idx = lane; idx < EDSZ; idx += 64) { A0[idx] = 0.f; A1[idx] = 0.f; }
  }
  __syncthreads();

  // per-chain state
  float u0c[2] = {0.f, 0.f}, u1c[2] = {0.f, 0.f};
  float v0c[2], v1c[2], m0c[2], m1c[2];
  int w0c[2] = {0, 0}, w1c[2] = {0, 0};
  int p0c[2] = {0, 0}, p1c[2] = {0, 0};
  int x0c[2] = {0, 0}, x1c[2] = {0, 0};
  unsigned long long ra0c[2] = {0ull, 0ull}, ra1c[2] = {0ull, 0ull};

  // ---------------- Phase 1: column reduction (interleaved) ----------------
  int y0c[2], y1c[2];
  {
    float c0[2] = {BIGF, BIGF}, c1[2] = {BIGF, BIGF};
    int yy0[2] = {0, 0}, yy1[2] = {0, 0};
    for (int r = 0; r < NNODE; ++r) {
      const float2 fa = *(const float2*)&DL[r * NNODE + cbase];
      const float2 fb = *(const float2*)&DgB[r * NNODE + cbase];
      if (fa.x < c0[0]) { c0[0] = fa.x; yy0[0] = r; }
      if (fa.y < c1[0]) { c1[0] = fa.y; yy1[0] = r; }
      if (fb.x < c0[1]) { c0[1] = fb.x; yy0[1] = r; }
      if (fb.y < c1[1]) { c1[1] = fb.y; yy1[1] = r; }
    }
#pragma unroll
    for (int c = 0; c < 2; ++c) {
      v0c[c] = c0[c]; v1c[c] = c1[c]; y0c[c] = yy0[c]; y1c[c] = yy1[c];
    }
  }

  // Greedy conflict-free assignment (sequential per chain; cheap)
#pragma unroll
  for (int c = 0; c < 2; ++c) {
    for (int j = 0; j < NNODE; ++j) {
      const int jl = j >> 1, jq = j & 1;
      const int i1 = __builtin_amdgcn_readlane(isel2(y0c[c], y1c[c], jq), jl);
      const int bit = i1 & 63;
      const unsigned long long msk = (i1 < 64) ? ra0c[c] : ra1c[c];
      if (!((msk >> bit) & 1ull)) {
        if (i1 < 64) ra0c[c] |= 1ull << bit; else ra1c[c] |= 1ull << bit;
        if (lane == jl) {
          if (jq == 0) p0c[c] = i1 + 1; else p1c[c] = i1 + 1;
        }
        if (lane == (i1 >> 1)) {
          if ((i1 & 1) == 0) x0c[c] = j + 1; else x1c[c] = j + 1;
        }
      }
    }
  }

  // ---------------- Phase 1r: reduction transfer (interleaved) ------------
  for (int ii = 0; ii < NNODE; ++ii) {
    const float2 fa = *(const float2*)&DL[ii * NNODE + cbase];
    const float2 fb = *(const float2*)&DgB[ii * NNODE + cbase];
    const float2 f[2] = {fa, fb};
#pragma unroll
    for (int c = 0; c < 2; ++c) {
      const int xj =
          __builtin_amdgcn_readlane(isel2(x0c[c], x1c[c], ii & 1), ii >> 1);
      const int j1 = xj - 1;  // -1 when inactive (never matches cbase)
      float r0 = fmaxf(f[c].x - v0c[c], 0.f);
      float r1 = fmaxf(f[c].y - v1c[c], 0.f);
      if (cbase + 0 == j1) r0 = BIGF;
      if (cbase + 1 == j1) r1 = BIGF;
      const unsigned ka = key_of(r0, cbase + 0);
      const unsigned kb = key_of(r1, cbase + 1);
      const unsigned kmin = wave_umin_key(ka < kb ? ka : kb);
      const int jm = (int)(kmin & 127u);
      const float umin = readlane_f32(fsel2(r0, r1, jm & 1), jm >> 1);
      if (xj != 0) {
        if (lane == (j1 >> 1)) {
          if ((j1 & 1) == 0) v0c[c] -= umin; else v1c[c] -= umin;
        }
        if (lane == (ii >> 1)) {
          if ((ii & 1) == 0) u0c[c] = umin; else u1c[c] = umin;
        }
      }
    }
  }

  // ---------------- Phase 1.5: augmenting row reduction (lockstep) --------
  {
    int budget[2];
#pragma unroll
    for (int c = 0; c < 2; ++c) {
      const int nf = NNODE - __builtin_popcountll(ra0c[c]) -
                     __builtin_popcountll(ra1c[c]);
      budget[c] = 2 * nf + 8;
    }
    for (;;) {
      int iRow[2];
      bool act[2];
#pragma unroll
      for (int c = 0; c < 2; ++c) {
        const unsigned long long fm0 = ~ra0c[c], fm1 = ~ra1c[c];
        act[c] = (budget[c] > 0) && ((fm0 | fm1) != 0ull);
        iRow[c] = fm0 ? __builtin_ctzll(fm0)
                      : (fm1 ? 64 + __builtin_ctzll(fm1) : 0);
        if (act[c]) budget[c]--;
      }
      if (!act[0] && !act[1]) break;
      const float2 fa = *(const float2*)&DL[iRow[0] * NNODE + cbase];
      const float2 fb = *(const float2*)&DgB[iRow[1] * NNODE + cbase];
      const float2 f[2] = {fa, fb};
#pragma unroll
      for (int c = 0; c < 2; ++c) {
        const int i = iRow[c];
        const float r0 = fmaxf(f[c].x - v0c[c], 0.f);
        const float r1 = fmaxf(f[c].y - v1c[c], 0.f);
        unsigned k1, k2;
        wave_umin2_key(key_of(r0, cbase + 0), key_of(r1, cbase + 1), k1, k2);
        const int j1 = (int)(k1 & 127u), j2 = (int)(k2 & 127u);
        const float u1v = readlane_f32(fsel2(r0, r1, j1 & 1), j1 >> 1);
        const float u2v = readlane_f32(fsel2(r0, r1, j2 & 1), j2 >> 1);
        int jt = j1;
        int i1 = __builtin_amdgcn_readlane(isel2(p0c[c], p1c[c], j1 & 1), j1 >> 1);
        const bool lowered = (u1v < u2v);
        if (!lowered && i1 != 0) {
          jt = j2;
          i1 = __builtin_amdgcn_readlane(isel2(p0c[c], p1c[c], j2 & 1), j2 >> 1);
        }
        if (act[c]) {
          if (lowered) {
            const float dv = u2v - u1v;
            if (lane == (j1 >> 1)) {
              if ((j1 & 1) == 0) v0c[c] -= dv; else v1c[c] -= dv;
            }
          }
          if (lane == (jt >> 1)) {
            if ((jt & 1) == 0) p0c[c] = i + 1; else p1c[c] = i + 1;
          }
          if (lane == (i >> 1)) {
            if ((i & 1) == 0) u0c[c] = u2v; else u1c[c] = u2v;
          }
          if (i < 64) ra0c[c] |= 1ull << i; else ra1c[c] |= 1ull << (i - 64);
          if (i1 != 0) {
            const int rr = i1 - 1;
            if (rr < 64) ra0c[c] &= ~(1ull << rr);
            else ra1c[c] &= ~(1ull << (rr - 64));
            if (lane == (rr >> 1)) {
              if ((rr & 1) == 0) u0c[c] = 0.f; else u1c[c] = 0.f;
            }
          }
        }
      }
    }
  }

  // ---------------- Phase 2: SAP, two chains in lockstep ----------------
  for (;;) {
    int iP[2];
    bool act[2];
#pragma unroll
    for (int c = 0; c < 2; ++c) {
      const unsigned long long fm0 = ~ra0c[c], fm1 = ~ra1c[c];
      act[c] = ((fm0 | fm1) != 0ull);
      iP[c] = fm0 ? (__builtin_ctzll(fm0) + 1)
                  : (fm1 ? (64 + __builtin_ctzll(fm1) + 1) : 1);
    }
    if (!act[0] && !act[1]) break;

    unsigned cused[2] = {0u, 0u}, rused[2] = {0u, 0u};
    int j0[2] = {0, 0}, i0[2];
    bool pact[2];
#pragma unroll
    for (int c = 0; c < 2; ++c) {
      m0c[c] = BIGF; m1c[c] = BIGF;
      i0[c] = iP[c];
      pact[c] = act[c];
    }
    for (int guard = 0; guard <= 2 * NNODE && (pact[0] || pact[1]); ++guard) {
      const float2 fa = *(const float2*)&DL[(i0[0] - 1) * NNODE + cbase];
      const float2 fb = *(const float2*)&DgB[(i0[1] - 1) * NNODE + cbase];
      const float2 f[2] = {fa, fb};
#pragma unroll
      for (int c = 0; c < 2; ++c) {
        // mark used column j0 (skip dummy) and row i0
        {
          const bool mk = pact[c] && j0[c] > 0 && lane == ((j0[c] - 1) >> 1);
          if (mk) {
            if (((j0[c] - 1) & 1) == 0) { cused[c] |= 1u; m0c[c] = BIGF; }
            else { cused[c] |= 2u; m1c[c] = BIGF; }
          }
          if (pact[c] && lane == ((i0[c] - 1) >> 1))
            rused[c] |= 1u << ((i0[c] - 1) & 1);
        }
        const float u_i0 =
            readlane_f32(fsel2(u0c[c], u1c[c], (i0[c] - 1) & 1), (i0[c] - 1) >> 1);
        const bool f0 = !(cused[c] & 1u), f1 = !(cused[c] & 2u);
        {
          float cur = fmaxf(f[c].x - u_i0 - v0c[c], 0.f);
          bool up = pact[c] && f0 && (cur < m0c[c]);
          m0c[c] = up ? cur : m0c[c];
          w0c[c] = up ? j0[c] : w0c[c];
        }
        {
          float cur = fmaxf(f[c].y - u_i0 - v1c[c], 0.f);
          bool up = pact[c] && f1 && (cur < m1c[c]);
          m1c[c] = up ? cur : m1c[c];
          w1c[c] = up ? j0[c] : w1c[c];
        }
        const unsigned ka = key_of(m0c[c], cbase + 0);
        const unsigned kb = key_of(m1c[c], cbase + 1);
        const unsigned kmin = wave_umin_key(ka < kb ? ka : kb);
        const int jcol = (int)(kmin & 127u);
        const float delta = readlane_f32(fsel2(m0c[c], m1c[c], jcol & 1), jcol >> 1);
        const int j1 = jcol + 1;
        if (pact[c]) {
          if (!f0) v0c[c] -= delta; else m0c[c] = fmaxf(m0c[c] - delta, 0.f);
          if (!f1) v1c[c] -= delta; else m1c[c] = fmaxf(m1c[c] - delta, 0.f);
          if (rused[c] & 1u) u0c[c] += delta;
          if (rused[c] & 2u) u1c[c] += delta;
        }
        const int pj1 = __builtin_amdgcn_readlane(
            isel2(p0c[c], p1c[c], (j1 - 1) & 1), (j1 - 1) >> 1);
        if (pact[c]) {
          j0[c] = j1;
          if (pj1 == 0) pact[c] = false;
          else i0[c] = pj1;
        }
      }
    }
    // augment per chain + mark row assigned
#pragma unroll
    for (int c = 0; c < 2; ++c) {
      if (act[c]) {
        int jc = j0[c];
        while (jc != 0) {
          const int cl = (jc - 1) >> 1, cq = (jc - 1) & 1;
          const int jp = __builtin_amdgcn_readlane(isel2(w0c[c], w1c[c], cq), cl);
          const int js = (jp == 0) ? 1 : jp;
          const int pvr = __builtin_amdgcn_readlane(
              isel2(p0c[c], p1c[c], (js - 1) & 1), (js - 1) >> 1);
          const int pv = (jp == 0) ? iP[c] : pvr;
          if (lane == cl) {
            if (cq == 0) p0c[c] = pv; else p1c[c] = pv;
          }
          jc = jp;
        }
        const int r = iP[c] - 1;
        if (r < 64) ra0c[c] |= 1ull << r; else ra1c[c] |= 1ull << (r - 64);
      }
    }
  }

  // ---------------- emit A and geds per chain ----------------
#pragma unroll
  for (int c = 0; c < 2; ++c) {
    const int b = 2 * bid + c;
    const float* ec = edit + (size_t)b * EDSZ;
    float* A = Aout + (size_t)b * EDSZ;
    double contrib = 0.0;
    const int pr[2] = {p0c[c], p1c[c]};
#pragma unroll
    for (int q = 0; q < 2; ++q) {
      const int j = cbase + q;
      const int i = pr[q] - 1;
      const float sub = ec[i * NP1 + j];
      const float di = ec[i * NP1 + NNODE] + ec[NNODE * NP1 + j];
      if (sub < di) {
        A[i * NP1 + j] = 1.f;
        contrib += (double)sub;
      } else {
        A[i * NP1 + NNODE] = 1.f;
        A[NNODE * NP1 + j] = 1.f;
        contrib += (double)di;
      }
    }
#pragma unroll
    for (int off = 32; off; off >>= 1) contrib += __shfl_xor(contrib, off);
    if (lane == 0) geds[b] = (float)(contrib / 256.0);
  }
}

// ---------------------------------------------------------------------------
// launch
// ---------------------------------------------------------------------------
extern "C" void kernel_launch(void* const* d_in, const int* in_sizes, int n_in,
                              void* d_out, int out_size, void* d_ws, size_t ws_size,
                              hipStream_t stream) {
  const float* x_s  = (const float*)d_in[0];
  const float* x_t  = (const float*)d_in[1];
  const float* W1   = (const float*)d_in[2];
  const float* b1   = (const float*)d_in[3];
  const float* W2   = (const float*)d_in[4];
  const float* b2   = (const float*)d_in[5];
  const float* virt = (const float*)d_in[6];

  const int M = BATCH * NNODE;  // 2048

  float* ws    = (float*)d_ws;
  float* h_s   = ws;
  float* h_t   = h_s + (size_t)M * DIM;
  float* e_s   = h_t + (size_t)M * DIM;
  float* e_t   = e_s + (size_t)M * DIM;
  float* e_v   = e_t + (size_t)M * DIM;           // 512
  float* d_raw = e_v + DIM;                       // 16*16641
  float* sums  = d_raw + (size_t)BATCH * EDSZ;    // 16
  float* Dg    = sums + 16;                       // 16*16384 (16B-aligned)

  float* Aout = (float*)d_out;
  float* edit = Aout + (size_t)BATCH * EDSZ;
  float* geds = edit + (size_t)BATCH * EDSZ;

  dim3 gblk(M / 64, DIM / 64, 2);  // (32, 8, 2)
  virt_embed<<<1, 256, 0, stream>>>(virt, W1, b1, W2, b2, e_v);
  gemm2_nt_relu<<<gblk, 256, 0, stream>>>(x_s, x_t, W1, b1, h_s, h_t, M, DIM, DIM);
  gemm2_nt_relu<<<gblk, 256, 0, stream>>>(h_s, h_t, W2, b2, e_s, e_t, M, DIM, DIM);

  cdist_kernel<<<dim3(5, 5, BATCH), 256, 0, stream>>>(e_s, e_t, e_v, d_raw);
  batch_sum<<<BATCH, 256, 0, stream>>>(d_raw, sums);
  normalize_kernel<<<(BATCH * EDSZ + 255) / 256, 256, 0, stream>>>(d_raw, sums, edit);
  build_D<<<(BATCH * NNODE * NNODE + 255) / 256, 256, 0, stream>>>(edit, Dg);
  lsap2_kernel<<<BATCH / 2, 64, 0, stream>>>(edit, Dg, Aout, geds);
}